// Round 23
// baseline (179.294 us; speedup 1.0000x reference)
//
#include <hip/hip_runtime.h>

typedef unsigned short u16;
typedef __attribute__((ext_vector_type(8))) short bf16x8;
typedef __attribute__((ext_vector_type(4))) float f32x4;
typedef __attribute__((ext_vector_type(2))) unsigned u32x2;
typedef __attribute__((ext_vector_type(4))) unsigned u32x4;

__device__ __forceinline__ u16 f2bf(float x) {
    union { float f; unsigned u; } v; v.f = x;
    unsigned r = v.u + 0x7FFF + ((v.u >> 16) & 1);
    return (u16)(r >> 16);
}

// pack 2 f32 -> 2 bf16 (RNE) in one op
__device__ __forceinline__ unsigned cvt_pk_bf16(float lo, float hi) {
    unsigned r;
    asm("v_cvt_pk_bf16_f32 %0, %1, %2" : "=v"(r) : "v"(lo), "v"(hi));
    return r;
}

// build PV A-operand directly from 8 exp'd scores (kv order matches permuted V)
__device__ __forceinline__ bf16x8 pk8(const f32x4& s0, const f32x4& s1) {
    union { u32x4 u; bf16x8 v; } x;
    x.u[0] = cvt_pk_bf16(s0[0], s0[1]);
    x.u[1] = cvt_pk_bf16(s0[2], s0[3]);
    x.u[2] = cvt_pk_bf16(s1[0], s1[1]);
    x.u[3] = cvt_pk_bf16(s1[2], s1[3]);
    return x.v;
}

// async global->LDS, 16B per lane; LDS dest = wave-uniform base + lane*16
__device__ __forceinline__ void gl_lds16(const u16* g, u16* l) {
    __builtin_amdgcn_global_load_lds((const __attribute__((address_space(1))) void*)g,
                                     (__attribute__((address_space(3))) void*)l, 16, 0, 0);
}

// ---------------------------------------------------------------------------
// Fused prep: blocks 0..5119 = fp32->bf16 convert of Xq (<1024) / Xkv;
// blocks 5120..5375 = weight transpose+convert (Wq / Wkv / Wp).
// ---------------------------------------------------------------------------
__global__ __launch_bounds__(256) void prep_kernel(const float* __restrict__ Xq,
                                                   const float* __restrict__ Xkv,
                                                   u16* __restrict__ oq,
                                                   u16* __restrict__ okv,
                                                   const float* __restrict__ Wq,
                                                   const float* __restrict__ Wkv,
                                                   const float* __restrict__ Wp,
                                                   u16* __restrict__ WqT,
                                                   u16* __restrict__ WkvT,
                                                   u16* __restrict__ WpT) {
    __shared__ float tile[64][65];
    int bid = blockIdx.x;
    int tid = threadIdx.x;
    if (bid < 5120) {
        const float* in;
        u16* out;
        size_t i;
        if (bid < 1024) {
            in = Xq; out = oq;
            i = ((size_t)bid * 256 + tid) * 8;
        } else {
            in = Xkv; out = okv;
            i = ((size_t)(bid - 1024) * 256 + tid) * 8;
        }
        const float4* p = (const float4*)(in + i);
        float4 a = p[0], b = p[1];
        u32x4 w = {cvt_pk_bf16(a.x, a.y), cvt_pk_bf16(a.z, a.w),
                   cvt_pk_bf16(b.x, b.y), cvt_pk_bf16(b.z, b.w)};
        *(u32x4*)(out + i) = w;
        return;
    }
    bid -= 5120;
    const float* in;
    u16* out;
    int R = 512, C, bx, by;
    if (bid < 64) {
        in = Wq; out = WqT; C = 512; bx = bid & 7; by = bid >> 3;
    } else if (bid < 192) {
        bid -= 64;
        in = Wkv; out = WkvT; C = 1024; bx = bid & 15; by = bid >> 4;
    } else {
        bid -= 192;
        in = Wp; out = WpT; C = 512; bx = bid & 7; by = bid >> 3;
    }
    int r0 = by * 64, c0 = bx * 64;
#pragma unroll
    for (int j = 0; j < 16; ++j) {
        int e = tid + j * 256;
        int row = e >> 6, col = e & 63;
        tile[row][col] = in[(size_t)(r0 + row) * C + c0 + col];
    }
    __syncthreads();
#pragma unroll
    for (int j = 0; j < 16; ++j) {
        int e = tid + j * 256;
        int row = e >> 6, col = e & 63;
        out[(size_t)(c0 + row) * R + r0 + col] = f2bf(tile[col][row]);
    }
}

// ---------------------------------------------------------------------------
// Merged Q + KV projection GEMM (one dispatch; block-range split).
// ---------------------------------------------------------------------------
__global__ __launch_bounds__(256) void gemm_qkv(const u16* __restrict__ Xqb,
                                                const u16* __restrict__ WqT,
                                                const float* __restrict__ bq,
                                                u16* __restrict__ Qb,
                                                const u16* __restrict__ Xkvb,
                                                const u16* __restrict__ WkvT,
                                                const float* __restrict__ bkv,
                                                u16* __restrict__ Kb,
                                                u16* __restrict__ Vt) {
    __shared__ u16 Al[128][64];
    __shared__ u16 Bl[128][64];
    int tid = threadIdx.x;
    int lane = tid & 63, wid = tid >> 6;
    int wr = wid >> 1, wc = wid & 1;
    int l15 = lane & 15, g = lane >> 4;
    int ldr = lane >> 3, ldc = (lane & 7) << 3;
    int bid = blockIdx.x;

    if (bid < 256) {
        // ---------------- Q path (128x64 tile, K=512) ----------------
        int bn = bid & 7, bm = bid >> 3;
        const int K = 512;
        f32x4 acc[4][2];
#pragma unroll
        for (int m = 0; m < 4; ++m)
#pragma unroll
            for (int n = 0; n < 2; ++n)
#pragma unroll
                for (int j = 0; j < 4; ++j) acc[m][n][j] = 0.f;

        for (int kt = 0; kt < 8; ++kt) {
            __syncthreads();
#pragma unroll
            for (int i = 0; i < 6; ++i) {
                int c = wid * 6 + i;
                if (c < 16) {
                    int row = c * 8 + ldr;
                    gl_lds16(Xqb + (size_t)(bm * 128 + row) * K + kt * 64 + ldc,
                             &Al[0][0] + c * 512);
                } else {
                    int cb = c - 16;
                    int row = cb * 8 + ldr;
                    gl_lds16(WqT + (size_t)(bn * 64 + row) * K + kt * 64 + ldc,
                             &Bl[0][0] + cb * 512);
                }
            }
            __syncthreads();

#pragma unroll
            for (int kk = 0; kk < 2; ++kk) {
                bf16x8 af[4], bfr[2];
#pragma unroll
                for (int m = 0; m < 4; ++m)
                    af[m] = *(const bf16x8*)&Al[wr * 64 + m * 16 + l15][kk * 32 + g * 8];
#pragma unroll
                for (int n = 0; n < 2; ++n)
                    bfr[n] = *(const bf16x8*)&Bl[wc * 32 + n * 16 + l15][kk * 32 + g * 8];
#pragma unroll
                for (int m = 0; m < 4; ++m)
#pragma unroll
                    for (int n = 0; n < 2; ++n)
                        acc[m][n] = __builtin_amdgcn_mfma_f32_16x16x32_bf16(af[m], bfr[n],
                                                                            acc[m][n], 0, 0, 0);
            }
        }

#pragma unroll
        for (int m = 0; m < 4; ++m)
#pragma unroll
            for (int n = 0; n < 2; ++n)
#pragma unroll
                for (int j = 0; j < 4; ++j) {
                    int row = bm * 128 + wr * 64 + m * 16 + g * 4 + j;
                    int col = bn * 64 + wc * 32 + n * 16 + l15;
                    float v = acc[m][n][j] + bq[col];
                    int b = row >> 10, q = row & 1023, h = col >> 6, d = col & 63;
                    Qb[(((size_t)((b * 8 + h) * 1024 + q)) << 6) + d] =
                        f2bf(v * 0.18033688011112042f);
                }
    } else {
        // ---------------- KV path (128x128 tile, K=512) ----------------
        int b2 = bid - 256;
        int bn = b2 & 7, bm = b2 >> 3;
        const int K = 512;
        f32x4 acc[4][4];
#pragma unroll
        for (int m = 0; m < 4; ++m)
#pragma unroll
            for (int n = 0; n < 4; ++n)
#pragma unroll
                for (int j = 0; j < 4; ++j) acc[m][n][j] = 0.f;

        for (int kt = 0; kt < 8; ++kt) {
            __syncthreads();
#pragma unroll
            for (int i = 0; i < 4; ++i) {
                int c = wid * 4 + i;
                int row = c * 8 + ldr;
                gl_lds16(Xkvb + (size_t)(bm * 128 + row) * K + kt * 64 + ldc,
                         &Al[0][0] + c * 512);
                gl_lds16(WkvT + (size_t)(bn * 128 + row) * K + kt * 64 + ldc,
                         &Bl[0][0] + c * 512);
            }
            __syncthreads();

#pragma unroll
            for (int kk = 0; kk < 2; ++kk) {
                bf16x8 af[4], bfr[4];
#pragma unroll
                for (int m = 0; m < 4; ++m)
                    af[m] = *(const bf16x8*)&Al[wr * 64 + m * 16 + l15][kk * 32 + g * 8];
#pragma unroll
                for (int n = 0; n < 4; ++n)
                    bfr[n] = *(const bf16x8*)&Bl[wc * 64 + n * 16 + l15][kk * 32 + g * 8];
#pragma unroll
                for (int m = 0; m < 4; ++m)
#pragma unroll
                    for (int n = 0; n < 4; ++n)
                        acc[m][n] = __builtin_amdgcn_mfma_f32_16x16x32_bf16(af[m], bfr[n],
                                                                            acc[m][n], 0, 0, 0);
            }
        }

#pragma unroll
        for (int m = 0; m < 4; ++m)
#pragma unroll
            for (int n = 0; n < 4; ++n)
#pragma unroll
                for (int j = 0; j < 4; ++j) {
                    int row = bm * 128 + wr * 64 + m * 16 + g * 4 + j;
                    int col = bn * 128 + wc * 64 + n * 16 + l15;
                    float v = acc[m][n][j] + bkv[col];
                    int b = row >> 12, kv = row & 4095;
                    if (col < 512) {
                        int h = col >> 6, d = col & 63;
                        Kb[(((size_t)((b * 8 + h) * 4096 + kv)) << 6) + d] = f2bf(v);
                    } else {
                        int c2 = col - 512;
                        int h = c2 >> 6, d = c2 & 63;
                        // phi^-1 within the kv-32 block (transpose_v fused)
                        int p = j | ((m & 1) << 2) | (g << 3);
                        int dkv = (kv & ~31) | p;
                        Vt[((size_t)(b * 8 + h) * 64 + d) * 4096 + dkv] = f2bf(v);
                    }
                }
    }
}

// ---------------------------------------------------------------------------
// GEMM 128x64 tile: output projection. out fp32 row-major + bias.
// ---------------------------------------------------------------------------
__global__ __launch_bounds__(256) void gemm_out(const u16* __restrict__ A,
                                                const u16* __restrict__ Bt,
                                                const float* __restrict__ bias,
                                                float* __restrict__ Cout,
                                                int M, int N, int K) {
    __shared__ u16 Al[128][64];
    __shared__ u16 Bl[64][64];
    int tid = threadIdx.x;
    int lane = tid & 63, wid = tid >> 6;
    int wr = wid >> 1, wc = wid & 1;
    int l15 = lane & 15, g = lane >> 4;
    int bm = blockIdx.y, bn = blockIdx.x;
    int ldr = lane >> 3, ldc = (lane & 7) << 3;

    f32x4 acc[4][2];
#pragma unroll
    for (int m = 0; m < 4; ++m)
#pragma unroll
        for (int n = 0; n < 2; ++n)
#pragma unroll
            for (int j = 0; j < 4; ++j) acc[m][n][j] = 0.f;

    int nK = K >> 6;
    for (int kt = 0; kt < nK; ++kt) {
        __syncthreads();
#pragma unroll
        for (int i = 0; i < 6; ++i) {
            int c = wid * 6 + i;
            if (c < 16) {
                int row = c * 8 + ldr;
                gl_lds16(A + (size_t)(bm * 128 + row) * K + kt * 64 + ldc, &Al[0][0] + c * 512);
            } else {
                int cb = c - 16;
                int row = cb * 8 + ldr;
                gl_lds16(Bt + (size_t)(bn * 64 + row) * K + kt * 64 + ldc, &Bl[0][0] + cb * 512);
            }
        }
        __syncthreads();

#pragma unroll
        for (int kk = 0; kk < 2; ++kk) {
            bf16x8 af[4], bfr[2];
#pragma unroll
            for (int m = 0; m < 4; ++m)
                af[m] = *(const bf16x8*)&Al[wr * 64 + m * 16 + l15][kk * 32 + g * 8];
#pragma unroll
            for (int n = 0; n < 2; ++n)
                bfr[n] = *(const bf16x8*)&Bl[wc * 32 + n * 16 + l15][kk * 32 + g * 8];
#pragma unroll
            for (int m = 0; m < 4; ++m)
#pragma unroll
                for (int n = 0; n < 2; ++n)
                    acc[m][n] =
                        __builtin_amdgcn_mfma_f32_16x16x32_bf16(af[m], bfr[n], acc[m][n], 0, 0, 0);
        }
    }

#pragma unroll
    for (int m = 0; m < 4; ++m)
#pragma unroll
        for (int n = 0; n < 2; ++n)
#pragma unroll
            for (int j = 0; j < 4; ++j) {
                int row = bm * 128 + wr * 64 + m * 16 + g * 4 + j;
                int col = bn * 64 + wc * 32 + n * 16 + l15;
                Cout[(size_t)row * N + col] = acc[m][n][j] + bias[col];
            }
}

// ---------------------------------------------------------------------------
// Flash attention v23 = frozen R14 geometry (512 blocks, qt16 x sp4,
// 4-batch, 64KB LDS, idx%8=h) + T4 counted-vmcnt double-buffer:
// kv-32 tiles, 2 buffers; RAW s_barrier (no implicit drain) + inline-asm
// s_waitcnt vmcnt(8) keeps next-tile DMAs in flight across the barrier.
// Per wave per tile issue order: [stage(cur):8] [pos:2] [stage(next):8];
// vmcnt(8) retires stage(cur)+pos (in-order), leaves stage(next) flying
// under the full compute phase. Barrier A orders reads-before-overwrite;
// barrier B publishes stage(cur). sched_barrier(0) pins issue order.
// kv-32 K/V LDS layouts R13/R18-validated; phi-direct PV, ones-MFMA,
// exp2-direct (frozen core). Last tile peels to vmcnt(0).
// ---------------------------------------------------------------------------
__global__ __launch_bounds__(256, 2) void attn_kernel(const u16* __restrict__ Qb,
                                                      const u16* __restrict__ Kb,
                                                      const u16* __restrict__ Vt,
                                                      const float* __restrict__ pos,
                                                      float* __restrict__ Opart,
                                                      float* __restrict__ Lp) {
    __shared__ u16 Klds[2][4][2048];  // [buf][b][32 kv x 64 d, slot-swizzled]
    __shared__ u16 Vlds[2][4][2048];  // [buf][b][32 x (2d x 32 kv), slot-swz]

    int idx = blockIdx.x;
    int h = idx & 7;  // idx%8 = h -> per-XCD K/V/pos locality (frozen regime)
    int rest = idx >> 3;
    int qt = rest & 15, sp = rest >> 4;
    int q0 = qt * 64;
    int kvbase = sp * 1024;
    int tid = threadIdx.x, lane = tid & 63, wid = tid >> 6;
    int l15 = lane & 15, g = lane >> 4;

    // Q fragments for all 4 batches (cols q = l15)
    bf16x8 aq[4][2];
#pragma unroll
    for (int b = 0; b < 4; ++b) {
        const u16* qp =
            Qb + (((size_t)((b * 8 + h) * 1024 + q0 + wid * 16 + l15)) << 6) + g * 8;
        aq[b][0] = *(const bf16x8*)(qp);
        aq[b][1] = *(const bf16x8*)(qp + 32);
    }

    f32x4 o[4][4];
    f32x4 lacc[4];
#pragma unroll
    for (int b = 0; b < 4; ++b) {
#pragma unroll
        for (int j = 0; j < 4; ++j) lacc[b][j] = 0.f;
#pragma unroll
        for (int n = 0; n < 4; ++n)
#pragma unroll
            for (int j = 0; j < 4; ++j) o[b][n][j] = 0.f;
    }

    // staging: wave wid owns batch b=wid; inverse-swizzled global sources
    const u16* Kg = Kb + ((size_t)(wid * 8 + h)) * 4096 * 64;
    const u16* Vg = Vt + ((size_t)(wid * 8 + h)) * 4096 * 64;
    int lr = lane >> 3;                 // row-in-chunk 0..7
    int lcs = ((lane & 7) ^ lr) << 3;   // K swizzled source col (u16 units)
    int vhalf = (lane >> 2) & 1;        // V: d parity
    int vslot = (lane & 3) ^ (lr & 3);  // V: source kv-octet (inverse swizzle)

    // pos row = q (l15), col = kv (contiguous -> f32x4)
    const float* posq =
        pos + (size_t)h * 1024 * 4096 + (size_t)(q0 + wid * 16 + l15) * 4096 + kvbase;

    const short one_s = (short)0x3F80;
    bf16x8 ones = {one_s, one_s, one_s, one_s, one_s, one_s, one_s, one_s};
    int sw = (l15 & 7) << 4;  // K read-side swizzle (bytes)

    auto STAGE = [&](int buf, int t) {
        int kv0 = kvbase + t * 32;
#pragma unroll
        for (int c = 0; c < 4; ++c) {
            gl_lds16(Kg + (size_t)(kv0 + c * 8 + lr) * 64 + lcs, &Klds[buf][wid][c * 512]);
            gl_lds16(Vg + (size_t)(2 * (c * 8 + lr) + vhalf) * 4096 + kv0 + vslot * 8,
                     &Vlds[buf][wid][c * 512]);
        }
    };

    // prologue: stage tile 0 (8 DMAs in flight)
    STAGE(0, 0);

    for (int kt = 0; kt < 32; ++kt) {
        int cur = kt & 1;
        __builtin_amdgcn_s_barrier();  // (A) all waves done reading buf[cur^1]
        // pos loads for THIS tile (issued before next-stage DMAs -> older)
        f32x4 zr[2];
#pragma unroll
        for (int n = 0; n < 2; ++n)
            zr[n] = *(const f32x4*)(posq + kt * 32 + n * 16 + g * 4);
        __builtin_amdgcn_sched_barrier(0);
        if (kt < 31) {
            STAGE(cur ^ 1, kt + 1);  // 8 DMAs into freed buffer; fly under compute
            __builtin_amdgcn_sched_barrier(0);
            asm volatile("s_waitcnt vmcnt(8)" ::: "memory");  // drain stage(cur)+pos only
        } else {
            __builtin_amdgcn_sched_barrier(0);
            asm volatile("s_waitcnt vmcnt(0)" ::: "memory");
        }
        __builtin_amdgcn_sched_barrier(0);
        __builtin_amdgcn_s_barrier();  // (B) all waves' stage(cur) landed
        __builtin_amdgcn_sched_barrier(0);

        // scale pos to exp2 domain
#pragma unroll
        for (int n = 0; n < 2; ++n)
#pragma unroll
            for (int j = 0; j < 4; ++j) zr[n][j] *= 1.44269504f;

#pragma unroll
        for (int b = 0; b < 4; ++b) {
            const char* KbL = (const char*)&Klds[cur][b][0];
            const char* VbL = (const char*)&Vlds[cur][b][0];

            // S^T = K_b . Q_b + pos   (rows kv = n*16+g*4+r, cols q = l15)
            f32x4 s[2];
            __builtin_amdgcn_s_setprio(1);
#pragma unroll
            for (int n = 0; n < 2; ++n) {
                bf16x8 kb0 = *(const bf16x8*)(KbL + (n * 16 + l15) * 128 + ((g * 16) ^ sw));
                bf16x8 kb1 = *(const bf16x8*)(KbL + (n * 16 + l15) * 128 + ((64 + g * 16) ^ sw));
                f32x4 t = __builtin_amdgcn_mfma_f32_16x16x32_bf16(kb0, aq[b][0], zr[n], 0, 0, 0);
                s[n] = __builtin_amdgcn_mfma_f32_16x16x32_bf16(kb1, aq[b][1], t, 0, 0, 0);
            }
            __builtin_amdgcn_s_setprio(0);

            // p = exp2(s)  (static max; scores bounded, no clamp)
#pragma unroll
            for (int n = 0; n < 2; ++n)
#pragma unroll
                for (int j = 0; j < 4; ++j) s[n][j] = __builtin_exp2f(s[n][j]);

            // PV A-operand directly from registers (phi-permuted Vt)
            bf16x8 pa = pk8(s[0], s[1]);  // kv 0..31 in A-operand k order

            __builtin_amdgcn_s_setprio(1);
#pragma unroll
            for (int n = 0; n < 4; ++n) {
                int vd = n * 16 + l15;
                int vr = vd >> 1;
                int vbyte = (vr << 7) + ((vd & 1) << 6) + (((g ^ (vr & 3)) & 3) << 4);
                bf16x8 vb = *(const bf16x8*)(VbL + vbyte);
                o[b][n] = __builtin_amdgcn_mfma_f32_16x16x32_bf16(pa, vb, o[b][n], 0, 0, 0);
            }
            lacc[b] = __builtin_amdgcn_mfma_f32_16x16x32_bf16(pa, ones, lacc[b], 0, 0, 0);
            __builtin_amdgcn_s_setprio(0);
        }
    }

    // epilogue: fp32 partials + l
#pragma unroll
    for (int b = 0; b < 4; ++b) {
        int obase = (sp * 32 + b * 8 + h) * 1024;
#pragma unroll
        for (int j = 0; j < 4; ++j) {
            int row = q0 + wid * 16 + g * 4 + j;
#pragma unroll
            for (int n = 0; n < 4; ++n)
                __builtin_nontemporal_store(o[b][n][j],
                                            &Opart[((size_t)(obase + row)) * 64 + n * 16 + l15]);
            if (l15 == 0) __builtin_nontemporal_store(lacc[b][j], &Lp[obase + row]);
        }
    }
}

// ---------------------------------------------------------------------------
// Merge 4 KV-splits, vectorized: thread owns 4 consecutive d (float4 loads
// per split, u16x4 store). out = (sum O_s) / (sum l_s); row mask. bf16 AO.
// ---------------------------------------------------------------------------
__global__ __launch_bounds__(256) void attn_combine(const float* __restrict__ Opart,
                                                    const float* __restrict__ Lp,
                                                    const int* __restrict__ mask,
                                                    u16* __restrict__ AO) {
    int tid = threadIdx.x;
    int d0 = (tid & 15) << 2;               // 0,4,..,60
    int r = blockIdx.x * 16 + (tid >> 4);   // (bh,q) row, 0..32767
    int bh = r >> 10, q = r & 1023;
    int b = bh >> 3, h = bh & 7;

    float L = 0.f;
    f32x4 val = {0.f, 0.f, 0.f, 0.f};
#pragma unroll
    for (int s2 = 0; s2 < 4; ++s2) {
        size_t rr = (size_t)(s2 * 32 + bh) * 1024 + q;
        L += Lp[rr];
        f32x4 v = *(const f32x4*)(Opart + rr * 64 + d0);
#pragma unroll
        for (int j = 0; j < 4; ++j) val[j] += v[j];
    }
    float inv = mask[b * 1024 + q] ? (1.0f / L) : 0.f;
    u32x2 w;
    w.x = cvt_pk_bf16(val[0] * inv, val[1] * inv);
    w.y = cvt_pk_bf16(val[2] * inv, val[3] * inv);
    *(u32x2*)(AO + ((size_t)(b * 1024 + q)) * 512 + h * 64 + d0) = w;
}

// ---------------------------------------------------------------------------
extern "C" void kernel_launch(void* const* d_in, const int* in_sizes, int n_in,
                              void* d_out, int out_size, void* d_ws, size_t ws_size,
                              hipStream_t stream) {
    const float* Xq = (const float*)d_in[0];
    const float* Xkv = (const float*)d_in[1];
    const int* mask = (const int*)d_in[2];
    const float* Wq = (const float*)d_in[3];
    const float* bq = (const float*)d_in[4];
    const float* Wkv = (const float*)d_in[5];
    const float* bkv = (const float*)d_in[6];
    const float* Wp = (const float*)d_in[7];
    const float* bp = (const float*)d_in[8];
    const float* pos = (const float*)d_in[9];
    float* out = (float*)d_out;

    char* ws = (char*)d_ws;
    u16* WqT = (u16*)(ws);                   // 0.5MB [512][512] bf16
    u16* WkvT = (u16*)(ws + 524288);         // 1MB   [1024][512]
    u16* WpT = (u16*)(ws + 1572864);         // 0.5MB
    u16* Qb = (u16*)(ws + 2097152);          // 4MB   [B,NH,Lq,HD]
    u16* Kb = (u16*)(ws + 6291456);          // 16MB  [B,NH,Lkv,HD]
    u16* Vt = (u16*)(ws + 23068672);         // 16MB  [B,NH,HD,Lkv] (phi-permuted, from gemm_qkv)
    u16* AO = (u16*)(ws + 39845888);         // 4MB   [B*Lq,E]
    float* Opart = (float*)(ws + 44040192);  // 32MB  [4sp][32bh][1024][64] fp32
    // dead-before-attn buffers aliased inside the Opart region:
    u16* Xkvb = (u16*)(ws + 44040192);       // 16MB  bf16 Xkv (dead after gemm_qkv)
    u16* Xqb = (u16*)(ws + 60817408);        // 4MB   bf16 Xq (dead after gemm_qkv)
    float* Lp = (float*)(ws + 111149056);    // 0.5MB [4sp][32bh][1024]

    prep_kernel<<<dim3(5376), 256, 0, stream>>>(Xq, Xkv, Xqb, Xkvb, Wq, Wkv, Wp, WqT, WkvT,
                                                WpT);
    gemm_qkv<<<dim3(1280), 256, 0, stream>>>(Xqb, WqT, bq, Qb, Xkvb, WkvT, bkv, Kb, Vt);
    attn_kernel<<<dim3(512), 256, 0, stream>>>(Qb, Kb, Vt, pos, Opart, Lp);
    attn_combine<<<dim3(2048), 256, 0, stream>>>(Opart, Lp, mask, AO);
    gemm_out<<<dim3(8, 32), 256, 0, stream>>>(AO, WpT, bp, out, 4096, 512, 512);
}

// Round 24
// 171.635 us; speedup vs baseline: 1.0446x; 1.0446x over previous
//
#include <hip/hip_runtime.h>

typedef unsigned short u16;
typedef __attribute__((ext_vector_type(8))) short bf16x8;
typedef __attribute__((ext_vector_type(4))) float f32x4;
typedef __attribute__((ext_vector_type(2))) unsigned u32x2;
typedef __attribute__((ext_vector_type(4))) unsigned u32x4;

__device__ __forceinline__ u16 f2bf(float x) {
    union { float f; unsigned u; } v; v.f = x;
    unsigned r = v.u + 0x7FFF + ((v.u >> 16) & 1);
    return (u16)(r >> 16);
}

// pack 2 f32 -> 2 bf16 (RNE) in one op
__device__ __forceinline__ unsigned cvt_pk_bf16(float lo, float hi) {
    unsigned r;
    asm("v_cvt_pk_bf16_f32 %0, %1, %2" : "=v"(r) : "v"(lo), "v"(hi));
    return r;
}

// build PV A-operand directly from 8 exp'd scores (kv order matches permuted V)
__device__ __forceinline__ bf16x8 pk8(const f32x4& s0, const f32x4& s1) {
    union { u32x4 u; bf16x8 v; } x;
    x.u[0] = cvt_pk_bf16(s0[0], s0[1]);
    x.u[1] = cvt_pk_bf16(s0[2], s0[3]);
    x.u[2] = cvt_pk_bf16(s1[0], s1[1]);
    x.u[3] = cvt_pk_bf16(s1[2], s1[3]);
    return x.v;
}

// async global->LDS, 16B per lane; LDS dest = wave-uniform base + lane*16
__device__ __forceinline__ void gl_lds16(const u16* g, u16* l) {
    __builtin_amdgcn_global_load_lds((const __attribute__((address_space(1))) void*)g,
                                     (__attribute__((address_space(3))) void*)l, 16, 0, 0);
}

// ---------------------------------------------------------------------------
// Fused prep: blocks 0..5119 = fp32->bf16 convert of Xq (<1024) / Xkv;
// blocks 5120..5375 = weight transpose+convert (Wq / Wkv / Wp).
// ---------------------------------------------------------------------------
__global__ __launch_bounds__(256) void prep_kernel(const float* __restrict__ Xq,
                                                   const float* __restrict__ Xkv,
                                                   u16* __restrict__ oq,
                                                   u16* __restrict__ okv,
                                                   const float* __restrict__ Wq,
                                                   const float* __restrict__ Wkv,
                                                   const float* __restrict__ Wp,
                                                   u16* __restrict__ WqT,
                                                   u16* __restrict__ WkvT,
                                                   u16* __restrict__ WpT) {
    __shared__ float tile[64][65];
    int bid = blockIdx.x;
    int tid = threadIdx.x;
    if (bid < 5120) {
        const float* in;
        u16* out;
        size_t i;
        if (bid < 1024) {
            in = Xq; out = oq;
            i = ((size_t)bid * 256 + tid) * 8;
        } else {
            in = Xkv; out = okv;
            i = ((size_t)(bid - 1024) * 256 + tid) * 8;
        }
        const float4* p = (const float4*)(in + i);
        float4 a = p[0], b = p[1];
        u32x4 w = {cvt_pk_bf16(a.x, a.y), cvt_pk_bf16(a.z, a.w),
                   cvt_pk_bf16(b.x, b.y), cvt_pk_bf16(b.z, b.w)};
        *(u32x4*)(out + i) = w;
        return;
    }
    bid -= 5120;
    const float* in;
    u16* out;
    int R = 512, C, bx, by;
    if (bid < 64) {
        in = Wq; out = WqT; C = 512; bx = bid & 7; by = bid >> 3;
    } else if (bid < 192) {
        bid -= 64;
        in = Wkv; out = WkvT; C = 1024; bx = bid & 15; by = bid >> 4;
    } else {
        bid -= 192;
        in = Wp; out = WpT; C = 512; bx = bid & 7; by = bid >> 3;
    }
    int r0 = by * 64, c0 = bx * 64;
#pragma unroll
    for (int j = 0; j < 16; ++j) {
        int e = tid + j * 256;
        int row = e >> 6, col = e & 63;
        tile[row][col] = in[(size_t)(r0 + row) * C + c0 + col];
    }
    __syncthreads();
#pragma unroll
    for (int j = 0; j < 16; ++j) {
        int e = tid + j * 256;
        int row = e >> 6, col = e & 63;
        out[(size_t)(c0 + row) * R + r0 + col] = f2bf(tile[col][row]);
    }
}

// ---------------------------------------------------------------------------
// Merged Q + KV projection GEMM (one dispatch; block-range split).
// blocks 0..255:    Q path  — 128x64 tiles; out bf16 *(0.125*log2e) -> Qb
// blocks 256..1279: KV path — 128x128 tiles; cols<512 -> K; cols>=512 ->
//                   Vt in phi-permuted [B,NH,HD,Lkv] (transpose_v fused)
// ---------------------------------------------------------------------------
__global__ __launch_bounds__(256) void gemm_qkv(const u16* __restrict__ Xqb,
                                                const u16* __restrict__ WqT,
                                                const float* __restrict__ bq,
                                                u16* __restrict__ Qb,
                                                const u16* __restrict__ Xkvb,
                                                const u16* __restrict__ WkvT,
                                                const float* __restrict__ bkv,
                                                u16* __restrict__ Kb,
                                                u16* __restrict__ Vt) {
    __shared__ u16 Al[128][64];
    __shared__ u16 Bl[128][64];
    int tid = threadIdx.x;
    int lane = tid & 63, wid = tid >> 6;
    int wr = wid >> 1, wc = wid & 1;
    int l15 = lane & 15, g = lane >> 4;
    int ldr = lane >> 3, ldc = (lane & 7) << 3;
    int bid = blockIdx.x;

    if (bid < 256) {
        // ---------------- Q path (128x64 tile, K=512) ----------------
        int bn = bid & 7, bm = bid >> 3;
        const int K = 512;
        f32x4 acc[4][2];
#pragma unroll
        for (int m = 0; m < 4; ++m)
#pragma unroll
            for (int n = 0; n < 2; ++n)
#pragma unroll
                for (int j = 0; j < 4; ++j) acc[m][n][j] = 0.f;

        for (int kt = 0; kt < 8; ++kt) {
            __syncthreads();
#pragma unroll
            for (int i = 0; i < 6; ++i) {
                int c = wid * 6 + i;
                if (c < 16) {
                    int row = c * 8 + ldr;
                    gl_lds16(Xqb + (size_t)(bm * 128 + row) * K + kt * 64 + ldc,
                             &Al[0][0] + c * 512);
                } else {
                    int cb = c - 16;
                    int row = cb * 8 + ldr;
                    gl_lds16(WqT + (size_t)(bn * 64 + row) * K + kt * 64 + ldc,
                             &Bl[0][0] + cb * 512);
                }
            }
            __syncthreads();

#pragma unroll
            for (int kk = 0; kk < 2; ++kk) {
                bf16x8 af[4], bfr[2];
#pragma unroll
                for (int m = 0; m < 4; ++m)
                    af[m] = *(const bf16x8*)&Al[wr * 64 + m * 16 + l15][kk * 32 + g * 8];
#pragma unroll
                for (int n = 0; n < 2; ++n)
                    bfr[n] = *(const bf16x8*)&Bl[wc * 32 + n * 16 + l15][kk * 32 + g * 8];
#pragma unroll
                for (int m = 0; m < 4; ++m)
#pragma unroll
                    for (int n = 0; n < 2; ++n)
                        acc[m][n] = __builtin_amdgcn_mfma_f32_16x16x32_bf16(af[m], bfr[n],
                                                                            acc[m][n], 0, 0, 0);
            }
        }

#pragma unroll
        for (int m = 0; m < 4; ++m)
#pragma unroll
            for (int n = 0; n < 2; ++n)
#pragma unroll
                for (int j = 0; j < 4; ++j) {
                    int row = bm * 128 + wr * 64 + m * 16 + g * 4 + j;
                    int col = bn * 64 + wc * 32 + n * 16 + l15;
                    float v = acc[m][n][j] + bq[col];
                    int b = row >> 10, q = row & 1023, h = col >> 6, d = col & 63;
                    Qb[(((size_t)((b * 8 + h) * 1024 + q)) << 6) + d] =
                        f2bf(v * 0.18033688011112042f);
                }
    } else {
        // ---------------- KV path (128x128 tile, K=512) ----------------
        int b2 = bid - 256;
        int bn = b2 & 7, bm = b2 >> 3;
        const int K = 512;
        f32x4 acc[4][4];
#pragma unroll
        for (int m = 0; m < 4; ++m)
#pragma unroll
            for (int n = 0; n < 4; ++n)
#pragma unroll
                for (int j = 0; j < 4; ++j) acc[m][n][j] = 0.f;

        for (int kt = 0; kt < 8; ++kt) {
            __syncthreads();
#pragma unroll
            for (int i = 0; i < 4; ++i) {
                int c = wid * 4 + i;
                int row = c * 8 + ldr;
                gl_lds16(Xkvb + (size_t)(bm * 128 + row) * K + kt * 64 + ldc,
                         &Al[0][0] + c * 512);
                gl_lds16(WkvT + (size_t)(bn * 128 + row) * K + kt * 64 + ldc,
                         &Bl[0][0] + c * 512);
            }
            __syncthreads();

#pragma unroll
            for (int kk = 0; kk < 2; ++kk) {
                bf16x8 af[4], bfr[4];
#pragma unroll
                for (int m = 0; m < 4; ++m)
                    af[m] = *(const bf16x8*)&Al[wr * 64 + m * 16 + l15][kk * 32 + g * 8];
#pragma unroll
                for (int n = 0; n < 4; ++n)
                    bfr[n] = *(const bf16x8*)&Bl[wc * 64 + n * 16 + l15][kk * 32 + g * 8];
#pragma unroll
                for (int m = 0; m < 4; ++m)
#pragma unroll
                    for (int n = 0; n < 4; ++n)
                        acc[m][n] = __builtin_amdgcn_mfma_f32_16x16x32_bf16(af[m], bfr[n],
                                                                            acc[m][n], 0, 0, 0);
            }
        }

#pragma unroll
        for (int m = 0; m < 4; ++m)
#pragma unroll
            for (int n = 0; n < 4; ++n)
#pragma unroll
                for (int j = 0; j < 4; ++j) {
                    int row = bm * 128 + wr * 64 + m * 16 + g * 4 + j;
                    int col = bn * 128 + wc * 64 + n * 16 + l15;
                    float v = acc[m][n][j] + bkv[col];
                    int b = row >> 12, kv = row & 4095;
                    if (col < 512) {
                        int h = col >> 6, d = col & 63;
                        Kb[(((size_t)((b * 8 + h) * 4096 + kv)) << 6) + d] = f2bf(v);
                    } else {
                        int c2 = col - 512;
                        int h = c2 >> 6, d = c2 & 63;
                        // phi^-1 within the kv-32 block (transpose_v fused)
                        int p = j | ((m & 1) << 2) | (g << 3);
                        int dkv = (kv & ~31) | p;
                        Vt[((size_t)(b * 8 + h) * 64 + d) * 4096 + dkv] = f2bf(v);
                    }
                }
    }
}

// ---------------------------------------------------------------------------
// GEMM 128x64 tile: output projection (all 256 CUs active).
// out fp32 row-major + bias.
// ---------------------------------------------------------------------------
__global__ __launch_bounds__(256) void gemm_out(const u16* __restrict__ A,
                                                const u16* __restrict__ Bt,
                                                const float* __restrict__ bias,
                                                float* __restrict__ Cout,
                                                int M, int N, int K) {
    __shared__ u16 Al[128][64];
    __shared__ u16 Bl[64][64];
    int tid = threadIdx.x;
    int lane = tid & 63, wid = tid >> 6;
    int wr = wid >> 1, wc = wid & 1;
    int l15 = lane & 15, g = lane >> 4;
    int bm = blockIdx.y, bn = blockIdx.x;
    int ldr = lane >> 3, ldc = (lane & 7) << 3;

    f32x4 acc[4][2];
#pragma unroll
    for (int m = 0; m < 4; ++m)
#pragma unroll
        for (int n = 0; n < 2; ++n)
#pragma unroll
            for (int j = 0; j < 4; ++j) acc[m][n][j] = 0.f;

    int nK = K >> 6;
    for (int kt = 0; kt < nK; ++kt) {
        __syncthreads();
#pragma unroll
        for (int i = 0; i < 6; ++i) {
            int c = wid * 6 + i;
            if (c < 16) {
                int row = c * 8 + ldr;
                gl_lds16(A + (size_t)(bm * 128 + row) * K + kt * 64 + ldc, &Al[0][0] + c * 512);
            } else {
                int cb = c - 16;
                int row = cb * 8 + ldr;
                gl_lds16(Bt + (size_t)(bn * 64 + row) * K + kt * 64 + ldc, &Bl[0][0] + cb * 512);
            }
        }
        __syncthreads();

#pragma unroll
        for (int kk = 0; kk < 2; ++kk) {
            bf16x8 af[4], bfr[2];
#pragma unroll
            for (int m = 0; m < 4; ++m)
                af[m] = *(const bf16x8*)&Al[wr * 64 + m * 16 + l15][kk * 32 + g * 8];
#pragma unroll
            for (int n = 0; n < 2; ++n)
                bfr[n] = *(const bf16x8*)&Bl[wc * 32 + n * 16 + l15][kk * 32 + g * 8];
#pragma unroll
            for (int m = 0; m < 4; ++m)
#pragma unroll
                for (int n = 0; n < 2; ++n)
                    acc[m][n] =
                        __builtin_amdgcn_mfma_f32_16x16x32_bf16(af[m], bfr[n], acc[m][n], 0, 0, 0);
        }
    }

#pragma unroll
    for (int m = 0; m < 4; ++m)
#pragma unroll
        for (int n = 0; n < 2; ++n)
#pragma unroll
            for (int j = 0; j < 4; ++j) {
                int row = bm * 128 + wr * 64 + m * 16 + g * 4 + j;
                int col = bn * 64 + wc * 32 + n * 16 + l15;
                Cout[(size_t)row * N + col] = acc[m][n][j] + bias[col];
            }
}

// ---------------------------------------------------------------------------
// Flash attention (frozen R14/R17 structure, ~96us): 4-batch fusion, kv
// tiles of 64, single-buffered global_load_lds (XOR-swizzled source), pos
// as QK C-operand (read once per element), phi-permuted register-direct PV,
// ones-MFMA denominator, exp2-direct, no clamp.
// ---------------------------------------------------------------------------
__global__ __launch_bounds__(256, 2) void attn_kernel(const u16* __restrict__ Qb,
                                                      const u16* __restrict__ Kb,
                                                      const u16* __restrict__ Vt,
                                                      const float* __restrict__ pos,
                                                      float* __restrict__ Opart,
                                                      float* __restrict__ Lp) {
    __shared__ u16 Klds[4][4096];  // [b][64 kv x 64 d, slot-swizzled]
    __shared__ u16 Vlds[4][4096];  // [b][64 d x 64 kv, slot-swizzled]

    int idx = blockIdx.x;
    int h = idx & 7;  // idx%8 = h -> per-XCD K/V/pos locality
    int rest = idx >> 3;
    int qt = rest & 15, sp = rest >> 4;
    int q0 = qt * 64;
    int kvbase = sp * 1024;
    int tid = threadIdx.x, lane = tid & 63, wid = tid >> 6;
    int l15 = lane & 15, g = lane >> 4;

    // Q fragments for all 4 batches (cols q = l15)
    bf16x8 aq[4][2];
#pragma unroll
    for (int b = 0; b < 4; ++b) {
        const u16* qp =
            Qb + (((size_t)((b * 8 + h) * 1024 + q0 + wid * 16 + l15)) << 6) + g * 8;
        aq[b][0] = *(const bf16x8*)(qp);
        aq[b][1] = *(const bf16x8*)(qp + 32);
    }

    f32x4 o[4][4];
    f32x4 lacc[4];
#pragma unroll
    for (int b = 0; b < 4; ++b) {
#pragma unroll
        for (int j = 0; j < 4; ++j) lacc[b][j] = 0.f;
#pragma unroll
        for (int n = 0; n < 4; ++n)
#pragma unroll
            for (int j = 0; j < 4; ++j) o[b][n][j] = 0.f;
    }

    // staging: wave wid owns batch b=wid; inverse-swizzled global source
    const u16* Kg = Kb + ((size_t)(wid * 8 + h)) * 4096 * 64;
    const u16* Vg = Vt + ((size_t)(wid * 8 + h)) * 4096 * 64;
    u16* KldsW = &Klds[wid][0];
    u16* VldsW = &Vlds[wid][0];
    int lr = lane >> 3;                // row-in-chunk 0..7
    int lcs = ((lane & 7) ^ lr) << 3;  // swizzled source col (u16 units)

    // pos row = q (l15), col = kv (contiguous -> f32x4)
    const float* posq =
        pos + (size_t)h * 1024 * 4096 + (size_t)(q0 + wid * 16 + l15) * 4096 + kvbase;

    const short one_s = (short)0x3F80;
    bf16x8 ones = {one_s, one_s, one_s, one_s, one_s, one_s, one_s, one_s};
    int sw = (l15 & 7) << 4;  // read-side swizzle (bytes)

    f32x4 zr[4];
    for (int kt = 0; kt < 16; ++kt) {
        int kv0 = kvbase + kt * 64;
        __syncthreads();  // all waves done reading prev tile's LDS
#pragma unroll
        for (int c = 0; c < 8; ++c)
            gl_lds16(Kg + (size_t)(kv0 + c * 8 + lr) * 64 + lcs, KldsW + c * 512);
#pragma unroll
        for (int c = 0; c < 8; ++c)
            gl_lds16(Vg + (size_t)(c * 8 + lr) * 4096 + kv0 + lcs, VldsW + c * 512);
        // pos tile for this kt (shared across all 4 b's), scaled to log2 units
#pragma unroll
        for (int n = 0; n < 4; ++n) {
            zr[n] = *(const f32x4*)(posq + kt * 64 + n * 16 + g * 4);
#pragma unroll
            for (int j = 0; j < 4; ++j) zr[n][j] *= 1.44269504f;
        }
        __syncthreads();  // drains vmcnt(0): K/V in LDS, zr loaded

#pragma unroll
        for (int b = 0; b < 4; ++b) {
            const char* KbL = (const char*)&Klds[b][0];
            const char* VbL = (const char*)&Vlds[b][0];

            // S^T = K_b . Q_b + pos   (rows kv = n*16+g*4+r, cols q = l15)
            f32x4 s[4];
            __builtin_amdgcn_s_setprio(1);
#pragma unroll
            for (int n = 0; n < 4; ++n) {
                bf16x8 kb0 = *(const bf16x8*)(KbL + (n * 16 + l15) * 128 + ((g * 16) ^ sw));
                bf16x8 kb1 = *(const bf16x8*)(KbL + (n * 16 + l15) * 128 + ((64 + g * 16) ^ sw));
                f32x4 t = __builtin_amdgcn_mfma_f32_16x16x32_bf16(kb0, aq[b][0], zr[n], 0, 0, 0);
                s[n] = __builtin_amdgcn_mfma_f32_16x16x32_bf16(kb1, aq[b][1], t, 0, 0, 0);
            }
            __builtin_amdgcn_s_setprio(0);

            // p = exp2(s)  (static max; scores bounded, no clamp)
#pragma unroll
            for (int n = 0; n < 4; ++n)
#pragma unroll
                for (int j = 0; j < 4; ++j) s[n][j] = __builtin_exp2f(s[n][j]);

            // PV A-operands directly from registers (phi-permuted Vt)
            bf16x8 pa0 = pk8(s[0], s[1]);   // kv 0..31
            bf16x8 pa1 = pk8(s[2], s[3]);   // kv 32..63

            __builtin_amdgcn_s_setprio(1);
#pragma unroll
            for (int n = 0; n < 4; ++n) {
                bf16x8 vb0 = *(const bf16x8*)(VbL + (n * 16 + l15) * 128 + ((g * 16) ^ sw));
                bf16x8 vb1 = *(const bf16x8*)(VbL + (n * 16 + l15) * 128 + ((64 + g * 16) ^ sw));
                o[b][n] = __builtin_amdgcn_mfma_f32_16x16x32_bf16(pa0, vb0, o[b][n], 0, 0, 0);
                o[b][n] = __builtin_amdgcn_mfma_f32_16x16x32_bf16(pa1, vb1, o[b][n], 0, 0, 0);
            }
            lacc[b] = __builtin_amdgcn_mfma_f32_16x16x32_bf16(pa0, ones, lacc[b], 0, 0, 0);
            lacc[b] = __builtin_amdgcn_mfma_f32_16x16x32_bf16(pa1, ones, lacc[b], 0, 0, 0);
            __builtin_amdgcn_s_setprio(0);
        }
    }

    // epilogue: fp32 partials + l
#pragma unroll
    for (int b = 0; b < 4; ++b) {
        int obase = (sp * 32 + b * 8 + h) * 1024;
#pragma unroll
        for (int j = 0; j < 4; ++j) {
            int row = q0 + wid * 16 + g * 4 + j;
#pragma unroll
            for (int n = 0; n < 4; ++n)
                __builtin_nontemporal_store(o[b][n][j],
                                            &Opart[((size_t)(obase + row)) * 64 + n * 16 + l15]);
            if (l15 == 0) __builtin_nontemporal_store(lacc[b][j], &Lp[obase + row]);
        }
    }
}

// ---------------------------------------------------------------------------
// Merge 4 KV-splits, vectorized: thread owns 4 consecutive d (float4 loads
// per split, u16x4 store). out = (sum O_s) / (sum l_s); row mask. bf16 AO.
// ---------------------------------------------------------------------------
__global__ __launch_bounds__(256) void attn_combine(const float* __restrict__ Opart,
                                                    const float* __restrict__ Lp,
                                                    const int* __restrict__ mask,
                                                    u16* __restrict__ AO) {
    int tid = threadIdx.x;
    int d0 = (tid & 15) << 2;               // 0,4,..,60
    int r = blockIdx.x * 16 + (tid >> 4);   // (bh,q) row, 0..32767
    int bh = r >> 10, q = r & 1023;
    int b = bh >> 3, h = bh & 7;

    float L = 0.f;
    f32x4 val = {0.f, 0.f, 0.f, 0.f};
#pragma unroll
    for (int s2 = 0; s2 < 4; ++s2) {
        size_t rr = (size_t)(s2 * 32 + bh) * 1024 + q;
        L += Lp[rr];
        f32x4 v = *(const f32x4*)(Opart + rr * 64 + d0);
#pragma unroll
        for (int j = 0; j < 4; ++j) val[j] += v[j];
    }
    float inv = mask[b * 1024 + q] ? (1.0f / L) : 0.f;
    u32x2 w;
    w.x = cvt_pk_bf16(val[0] * inv, val[1] * inv);
    w.y = cvt_pk_bf16(val[2] * inv, val[3] * inv);
    *(u32x2*)(AO + ((size_t)(b * 1024 + q)) * 512 + h * 64 + d0) = w;
}

// ---------------------------------------------------------------------------
extern "C" void kernel_launch(void* const* d_in, const int* in_sizes, int n_in,
                              void* d_out, int out_size, void* d_ws, size_t ws_size,
                              hipStream_t stream) {
    const float* Xq = (const float*)d_in[0];
    const float* Xkv = (const float*)d_in[1];
    const int* mask = (const int*)d_in[2];
    const float* Wq = (const float*)d_in[3];
    const float* bq = (const float*)d_in[4];
    const float* Wkv = (const float*)d_in[5];
    const float* bkv = (const float*)d_in[6];
    const float* Wp = (const float*)d_in[7];
    const float* bp = (const float*)d_in[8];
    const float* pos = (const float*)d_in[9];
    float* out = (float*)d_out;

    char* ws = (char*)d_ws;
    u16* WqT = (u16*)(ws);                   // 0.5MB [512][512] bf16
    u16* WkvT = (u16*)(ws + 524288);         // 1MB   [1024][512]
    u16* WpT = (u16*)(ws + 1572864);         // 0.5MB
    u16* Qb = (u16*)(ws + 2097152);          // 4MB   [B,NH,Lq,HD]
    u16* Kb = (u16*)(ws + 6291456);          // 16MB  [B,NH,Lkv,HD]
    u16* Vt = (u16*)(ws + 23068672);         // 16MB  [B,NH,HD,Lkv] (phi-permuted, from gemm_qkv)
    u16* AO = (u16*)(ws + 39845888);         // 4MB   [B*Lq,E]
    float* Opart = (float*)(ws + 44040192);  // 32MB  [4sp][32bh][1024][64] fp32
    // dead-before-attn buffers aliased inside the Opart region:
    u16* Xkvb = (u16*)(ws + 44040192);       // 16MB  bf16 Xkv (dead after gemm_qkv)
    u16* Xqb = (u16*)(ws + 60817408);        // 4MB   bf16 Xq (dead after gemm_qkv)
    float* Lp = (float*)(ws + 111149056);    // 0.5MB [4sp][32bh][1024]

    prep_kernel<<<dim3(5376), 256, 0, stream>>>(Xq, Xkv, Xqb, Xkvb, Wq, Wkv, Wp, WqT, WkvT,
                                                WpT);
    gemm_qkv<<<dim3(1280), 256, 0, stream>>>(Xqb, WqT, bq, Qb, Xkvb, WkvT, bkv, Kb, Vt);
    attn_kernel<<<dim3(512), 256, 0, stream>>>(Qb, Kb, Vt, pos, Opart, Lp);
    attn_combine<<<dim3(2048), 256, 0, stream>>>(Opart, Lp, mask, AO);
    gemm_out<<<dim3(8, 32), 256, 0, stream>>>(AO, WpT, bp, out, 4096, 512, 512);
}